// Round 9
// baseline (548.355 us; speedup 1.0000x reference)
//
#include <hip/hip_runtime.h>
#include <hip/hip_bf16.h>

#define HH 1024
#define NHEADS 8
#define HDIM 128
#define BB 4
#define TT 2048
#define MROWS (BB*TT)   // 8192

typedef __bf16 bf16;
typedef __bf16 bf16x4 __attribute__((ext_vector_type(4)));
typedef __bf16 bf16x8 __attribute__((ext_vector_type(8)));
typedef float floatx4 __attribute__((ext_vector_type(4)));

// async global->LDS DMA, 16B/lane; lds dest = wave-uniform base + lane*16
__device__ __forceinline__ void gl2lds16(const void* g, void* l) {
    __builtin_amdgcn_global_load_lds(
        (const __attribute__((address_space(1))) unsigned int*)g,
        (__attribute__((address_space(3))) unsigned int*)l, 16, 0, 0);
}

// ---------------- LayerNorm stats: one block per row, writes (mu, rs) ----------------
__global__ __launch_bounds__(256) void lnstat_k(const float* __restrict__ x,
                                                float* __restrict__ stats) {
    int row = blockIdx.x;
    int t = threadIdx.x;
    float4 v4 = ((const float4*)(x + (size_t)row * HH))[t];
    const float* v = (const float*)&v4;
    float s = v[0] + v[1] + v[2] + v[3];
    float s2 = v[0]*v[0] + v[1]*v[1] + v[2]*v[2] + v[3]*v[3];
#pragma unroll
    for (int off = 32; off > 0; off >>= 1) {
        s  += __shfl_down(s,  off);
        s2 += __shfl_down(s2, off);
    }
    __shared__ float red[8];
    if ((t & 63) == 0) { red[t >> 6] = s; red[(t >> 6) + 4] = s2; }
    __syncthreads();
    if (t == 0) {
        s  = red[0] + red[1] + red[2] + red[3];
        s2 = red[4] + red[5] + red[6] + red[7];
        float mu  = s * (1.f / HH);
        float var = s2 * (1.f / HH) - mu * mu;
        stats[row * 2]     = mu;
        stats[row * 2 + 1] = rsqrtf(var + 1e-5f);
    }
}

// ---------------- Weight convert f32 -> bf16 (1024x1024) ----------------
__global__ __launch_bounds__(256) void convw_k(const float* __restrict__ W,
                                               bf16* __restrict__ Wb) {
    int idx = blockIdx.x * 256 + threadIdx.x;
    float4 v4 = ((const float4*)W)[idx];
    const float* v = (const float*)&v4;
    bf16x4 o;
#pragma unroll
    for (int z = 0; z < 4; z++) o[z] = (bf16)v[z];
    ((bf16x4*)Wb)[idx] = o;
}

// -------- Fused QKV GEMM (M=8192, N=3072, K=1024), LN fused on A --------
// A staged f32->LN->bf16 (padded tile, VGPR-prefetched); W_qkv bf16 via DMA
// (unpadded, source-swizzled). Block's column range selects output: Q / K / V^T.
__global__ __launch_bounds__(256) void gemm_qkv_k(const float* __restrict__ A,
                                                  const float* __restrict__ stats,
                                                  const float* __restrict__ g,
                                                  const float* __restrict__ be,
                                                  const bf16* __restrict__ W,
                                                  bf16* __restrict__ Qb,
                                                  bf16* __restrict__ Kb,
                                                  bf16* __restrict__ Vb) {
    const int K = HH;
    __shared__ __align__(16) bf16 As[128][40];
    __shared__ __align__(16) bf16 Ws[128 * 32];
    int m0 = blockIdx.x * 128, n0 = blockIdx.y * 128;
    int t = threadIdx.x, lane = t & 63, w = t >> 6;
    int wm = w >> 1, wn = w & 1;
    int quad = lane >> 4, cl = lane & 15, kq = quad * 8;
    int r0 = t >> 3, c0 = (t & 7) * 4;                  // A staging
    int rW0 = w * 16 + (lane >> 2);                     // W DMA rows (+i*64)
    int xw = (((lane & 3) ^ ((lane >> 3) & 3)) * 8);    // swizzled source col
    char* WsB = (char*)Ws + w * 1024;
    int pc = (quad ^ ((cl >> 1) & 3)) * 8;              // W frag phys chunk
    float mu[4], rs[4];
#pragma unroll
    for (int i = 0; i < 4; i++) {
        int r = m0 + r0 + i * 32;
        mu[i] = stats[r * 2]; rs[i] = stats[r * 2 + 1];
    }
    float4 va[4], vg, vb4;
    auto fetch = [&](int k0) {
        vg  = *(const float4*)&g[k0 + c0];
        vb4 = *(const float4*)&be[k0 + c0];
#pragma unroll
        for (int i = 0; i < 4; i++)
            va[i] = *(const float4*)&A[(size_t)(m0 + r0 + i * 32) * K + k0 + c0];
    };
    fetch(0);
    floatx4 acc[4][4] = {};
    for (int k0 = 0; k0 < K; k0 += 32) {
        __syncthreads();
#pragma unroll
        for (int i = 0; i < 2; i++)
            gl2lds16(&W[(size_t)(n0 + rW0 + i * 64) * K + k0 + xw], WsB + i * 4096);
#pragma unroll
        for (int i = 0; i < 4; i++) {
            const float* pa = (const float*)&va[i];
            const float* pg = (const float*)&vg;
            const float* pb = (const float*)&vb4;
            bf16x4 nv;
#pragma unroll
            for (int z = 0; z < 4; z++)
                nv[z] = (bf16)((pa[z] - mu[i]) * rs[i] * pg[z] + pb[z]);
            *(bf16x4*)&As[r0 + i * 32][c0] = nv;
        }
        if (k0 + 32 < K) fetch(k0 + 32);
        __syncthreads();
        bf16x8 af[4], bfr[4];
#pragma unroll
        for (int i = 0; i < 4; i++) af[i]  = *(const bf16x8*)&As[wm * 64 + i * 16 + cl][kq];
#pragma unroll
        for (int j = 0; j < 4; j++) bfr[j] = *(const bf16x8*)&Ws[(wn * 64 + j * 16 + cl) * 32 + pc];
#pragma unroll
        for (int i = 0; i < 4; i++)
#pragma unroll
            for (int j = 0; j < 4; j++)
                acc[i][j] = __builtin_amdgcn_mfma_f32_16x16x32_bf16(af[i], bfr[j], acc[i][j], 0, 0, 0);
    }
    // epilogue: n0 in [0,1024) -> Q, [1024,2048) -> K, [2048,3072) -> V^T
#pragma unroll
    for (int i = 0; i < 4; i++)
#pragma unroll
        for (int j = 0; j < 4; j++) {
            int gr = m0 + wm * 64 + i * 16 + quad * 4;
            int gn = n0 + wn * 64 + j * 16 + cl;
            if (n0 < 1024) {
#pragma unroll
                for (int rg = 0; rg < 4; rg++)
                    Qb[(size_t)(gr + rg) * HH + gn] = (bf16)acc[i][j][rg];
            } else if (n0 < 2048) {
#pragma unroll
                for (int rg = 0; rg < 4; rg++)
                    Kb[(size_t)(gr + rg) * HH + (gn - 1024)] = (bf16)acc[i][j][rg];
            } else {
                int gc = gn - 2048;
                int bb2 = gr >> 11, tt2 = gr & 2047;
                int hh2 = gc >> 7,  dd2 = gc & 127;
                bf16x4 o4;
#pragma unroll
                for (int rg = 0; rg < 4; rg++) o4[rg] = (bf16)acc[i][j][rg];
                *(bf16x4*)&Vb[((size_t)(bb2 * NHEADS + hh2) * HDIM + dd2) * TT + tt2] = o4;
            }
        }
}

// ------- 128x128 final GEMM (DMA staging): out_f32 = A_bf16 * Wb_bf16^T + R_f32 -------
__global__ __launch_bounds__(256) void gemm_finbf_k(const bf16* __restrict__ A,
                                                    const bf16* __restrict__ W,
                                                    const float* __restrict__ R,
                                                    float* __restrict__ C) {
    const int K = HH, N = HH;
    __shared__ __align__(16) bf16 As[128 * 32];
    __shared__ __align__(16) bf16 Ws[128 * 32];
    int m0 = blockIdx.x * 128, n0 = blockIdx.y * 128;
    int t = threadIdx.x, lane = t & 63, w = t >> 6;
    int wm = w >> 1, wn = w & 1;
    int quad = lane >> 4, cl = lane & 15;
    int rA0 = w * 16 + (lane >> 2);
    int xa = (((lane & 3) ^ ((lane >> 3) & 3)) * 8);
    char* AsB = (char*)As + w * 1024;
    char* WsB = (char*)Ws + w * 1024;
    int pc = (quad ^ ((cl >> 1) & 3)) * 8;
    floatx4 acc[4][4] = {};
    for (int k0 = 0; k0 < K; k0 += 32) {
        __syncthreads();
#pragma unroll
        for (int i = 0; i < 2; i++) {
            gl2lds16(&A[(size_t)(m0 + rA0 + i * 64) * K + k0 + xa], AsB + i * 4096);
            gl2lds16(&W[(size_t)(n0 + rA0 + i * 64) * K + k0 + xa], WsB + i * 4096);
        }
        __syncthreads();
        bf16x8 af[4], bfr[4];
#pragma unroll
        for (int i = 0; i < 4; i++) af[i]  = *(const bf16x8*)&As[(wm * 64 + i * 16 + cl) * 32 + pc];
#pragma unroll
        for (int j = 0; j < 4; j++) bfr[j] = *(const bf16x8*)&Ws[(wn * 64 + j * 16 + cl) * 32 + pc];
#pragma unroll
        for (int i = 0; i < 4; i++)
#pragma unroll
            for (int j = 0; j < 4; j++)
                acc[i][j] = __builtin_amdgcn_mfma_f32_16x16x32_bf16(af[i], bfr[j], acc[i][j], 0, 0, 0);
    }
#pragma unroll
    for (int i = 0; i < 4; i++)
#pragma unroll
        for (int j = 0; j < 4; j++)
#pragma unroll
            for (int rg = 0; rg < 4; rg++) {
                int gr = m0 + wm * 64 + i * 16 + quad * 4 + rg;
                int gc = n0 + wn * 64 + j * 16 + cl;
                C[(size_t)gr * N + gc] = acc[i][j][rg] + R[(size_t)gr * N + gc];
            }
}

// ---- Flash attention (causal): 128-row Q tile, Q frags from global, ----
// ---- single-buffered padded K/V with VGPR prefetch, 3 blocks/CU ----
__global__ __launch_bounds__(256, 3) void attn_k(const bf16* __restrict__ Q,
                                                 const bf16* __restrict__ Kg,
                                                 const bf16* __restrict__ Vt,
                                                 bf16* __restrict__ O) {
    __shared__ __align__(16) bf16 Ks[64 * 136];   // 17408 B
    __shared__ __align__(16) bf16 Vs[128 * 72];   // 18432 B -> 35840 B total

    int qt = gridDim.x - 1 - blockIdx.x;  // longest blocks first
    int h = blockIdx.y, b = blockIdx.z;
    int t = threadIdx.x, lane = t & 63, w = t >> 6;
    int quad = lane >> 4, cl = lane & 15;
    size_t rowbase = (size_t)b * TT;
    int q0 = qt * 128;
    size_t hcol = (size_t)h * HDIM;
    size_t vtbase = (size_t)(b * NHEADS + h) * HDIM * TT;

    // Q fragments straight from global (one-time; L2-warm)
    bf16x8 qf[4][2];
#pragma unroll
    for (int kk = 0; kk < 4; kk++)
#pragma unroll
        for (int g = 0; g < 2; g++)
            qf[kk][g] = *(const bf16x8*)&Q[(rowbase + q0 + w * 32 + g * 16 + cl) * HH + hcol + kk * 32 + quad * 8];

    float m_i[2] = {-1e30f, -1e30f}, l_i[2] = {0.f, 0.f};
    floatx4 acc[8][2] = {};
    const float scale = 0.08838834764831845f;  // 1/sqrt(128)

    bf16x8 kr[4], vr[4];
    auto fetch = [&](int ktf) {
#pragma unroll
        for (int i = 0; i < 4; i++) {
            int e = t + i * 256;
            kr[i] = *(const bf16x8*)&Kg[(rowbase + (size_t)ktf * 64 + (e >> 4)) * HH + hcol + (e & 15) * 8];
            vr[i] = *(const bf16x8*)&Vt[vtbase + (size_t)(e >> 3) * TT + ktf * 64 + (e & 7) * 8];
        }
    };
    fetch(0);
    int ktmax = 2 * qt + 1;

    for (int kt = 0; kt <= ktmax; kt++) {
        __syncthreads();  // prev iter's frag reads complete
#pragma unroll
        for (int i = 0; i < 4; i++) {
            int e = t + i * 256;
            *(bf16x8*)&Ks[(e >> 4) * 136 + (e & 15) * 8] = kr[i];
            *(bf16x8*)&Vs[(e >> 3) * 72 + (e & 7) * 8]   = vr[i];
        }
        if (kt < ktmax) fetch(kt + 1);  // in flight across whole body
        __syncthreads();

        // S^T: A = K-frag (shared by both q-groups), B = Q-frag
        floatx4 sacc[2][4] = {};
#pragma unroll
        for (int kk = 0; kk < 4; kk++)
#pragma unroll
            for (int jj = 0; jj < 4; jj++) {
                bf16x8 ak = *(const bf16x8*)&Ks[(jj * 16 + cl) * 136 + kk * 32 + quad * 8];
                sacc[0][jj] = __builtin_amdgcn_mfma_f32_16x16x32_bf16(ak, qf[kk][0], sacc[0][jj], 0, 0, 0);
                sacc[1][jj] = __builtin_amdgcn_mfma_f32_16x16x32_bf16(ak, qf[kk][1], sacc[1][jj], 0, 0, 0);
            }

        float pp[2][4][4], alpha[2];
        bool diag = (kt >= 2 * qt);
#pragma unroll
        for (int g = 0; g < 2; g++) {
            int qglob = q0 + w * 32 + g * 16 + cl;
            float mx = -1e30f;
#pragma unroll
            for (int jj = 0; jj < 4; jj++)
#pragma unroll
                for (int rg = 0; rg < 4; rg++) {
                    float sv = sacc[g][jj][rg] * scale;
                    if (diag && (kt * 64 + jj * 16 + quad * 4 + rg) > qglob) sv = -1e30f;
                    pp[g][jj][rg] = sv;
                    mx = fmaxf(mx, sv);
                }
            mx = fmaxf(mx, __shfl_xor(mx, 16));
            mx = fmaxf(mx, __shfl_xor(mx, 32));
            float mn = fmaxf(m_i[g], mx);
            alpha[g] = __expf(m_i[g] - mn);
            m_i[g] = mn;
            float sum = 0.f;
#pragma unroll
            for (int jj = 0; jj < 4; jj++)
#pragma unroll
                for (int rg = 0; rg < 4; rg++) {
                    float pe = __expf(pp[g][jj][rg] - mn);
                    pp[g][jj][rg] = pe;
                    sum += pe;
                }
            sum += __shfl_xor(sum, 16);
            sum += __shfl_xor(sum, 32);
            l_i[g] = l_i[g] * alpha[g] + sum;
        }

        int pk[2][4][2];
#pragma unroll
        for (int g = 0; g < 2; g++)
#pragma unroll
            for (int jj = 0; jj < 4; jj++) {
                union { bf16x4 v; int i2[2]; } u;
#pragma unroll
                for (int rg = 0; rg < 4; rg++) u.v[rg] = (bf16)pp[g][jj][rg];
                pk[g][jj][0] = u.i2[0];
                pk[g][jj][1] = u.i2[1];
            }
#pragma unroll
        for (int nt = 0; nt < 8; nt++) {
            acc[nt][0] *= alpha[0];
            acc[nt][1] *= alpha[1];
        }

        int La = ((2 * quad) & 3) * 16 + cl;
        int Lb = ((2 * quad + 1) & 3) * 16 + cl;
        bool hi = (quad >> 1) & 1;
#pragma unroll
        for (int kti = 0; kti < 2; kti++) {
            int j0 = kti * 2, j1 = kti * 2 + 1;
            union { bf16x8 v; int i4[4]; } pu[2];
#pragma unroll
            for (int g = 0; g < 2; g++) {
                int a0x = __shfl(pk[g][j0][0], La), a0y = __shfl(pk[g][j0][1], La);
                int a1x = __shfl(pk[g][j1][0], La), a1y = __shfl(pk[g][j1][1], La);
                int b0x = __shfl(pk[g][j0][0], Lb), b0y = __shfl(pk[g][j0][1], Lb);
                int b1x = __shfl(pk[g][j1][0], Lb), b1y = __shfl(pk[g][j1][1], Lb);
                pu[g].i4[0] = hi ? a1x : a0x;
                pu[g].i4[1] = hi ? a1y : a0y;
                pu[g].i4[2] = hi ? b1x : b0x;
                pu[g].i4[3] = hi ? b1y : b0y;
            }
#pragma unroll
            for (int nt = 0; nt < 8; nt++) {
                bf16x8 av = *(const bf16x8*)&Vs[(nt * 16 + cl) * 72 + kti * 32 + quad * 8];
                acc[nt][0] = __builtin_amdgcn_mfma_f32_16x16x32_bf16(av, pu[0].v, acc[nt][0], 0, 0, 0);
                acc[nt][1] = __builtin_amdgcn_mfma_f32_16x16x32_bf16(av, pu[1].v, acc[nt][1], 0, 0, 0);
            }
        }
    }

    float linv[2] = {1.f / l_i[0], 1.f / l_i[1]};
#pragma unroll
    for (int g = 0; g < 2; g++)
#pragma unroll
        for (int nt = 0; nt < 8; nt++) {
            bf16x4 o4;
#pragma unroll
            for (int rg = 0; rg < 4; rg++) o4[rg] = (bf16)(acc[nt][g][rg] * linv[g]);
            *(bf16x4*)&O[(rowbase + q0 + w * 32 + g * 16 + cl) * HH + hcol + nt * 16 + quad * 4] = o4;
        }
}

extern "C" void kernel_launch(void* const* d_in, const int* in_sizes, int n_in,
                              void* d_out, int out_size, void* d_ws, size_t ws_size,
                              hipStream_t stream) {
    const float* x     = (const float*)d_in[0];
    const float* gamma = (const float*)d_in[1];
    const float* beta  = (const float*)d_in[2];
    const float* Wq    = (const float*)d_in[3];
    const float* Wk    = (const float*)d_in[4];
    const float* Wv    = (const float*)d_in[5];
    const float* Wo    = (const float*)d_in[6];
    float* out = (float*)d_out;

    const size_t NELEM = (size_t)MROWS * HH;  // 8.39M
    const size_t NW    = (size_t)HH * HH;     // 1.05M
    // ws (33.7 MB): Qb bf16 + Vb bf16 + stats f32 (64 KB).
    // d_out (33.5 MB f32): Kb bf16 [0,16.8M) + Wqkv bf16 [16.8M,23.1M) —
    // both dead before the final GEMM writes d_out. Attn output aliases Qb;
    // Wo-bf16 parked in Vb (dead after attn).
    bf16*  Qb    = (bf16*)d_ws;
    bf16*  Vb    = Qb + NELEM;           // V^T layout [b][h][d][T]
    float* stats = (float*)(Vb + NELEM);
    bf16*  Kb    = (bf16*)d_out;
    bf16*  Wqkv  = (bf16*)d_out + NELEM; // 3072x1024 bf16

    lnstat_k<<<MROWS, 256, 0, stream>>>(x, stats);
    convw_k<<<NW / 1024, 256, 0, stream>>>(Wq, Wqkv);
    convw_k<<<NW / 1024, 256, 0, stream>>>(Wk, Wqkv + NW);
    convw_k<<<NW / 1024, 256, 0, stream>>>(Wv, Wqkv + 2 * NW);
    gemm_qkv_k<<<dim3(MROWS / 128, 24), 256, 0, stream>>>(x, stats, gamma, beta, Wqkv, Qb, Kb, Vb);
    attn_k<<<dim3(TT / 128, NHEADS, BB), 256, 0, stream>>>(Qb, Kb, Vb, Qb);
    convw_k<<<NW / 1024, 256, 0, stream>>>(Wo, Vb);
    gemm_finbf_k<<<dim3(MROWS / 128, HH / 128), 256, 0, stream>>>(Qb, Vb, x, out);
}

// Round 10
// 357.556 us; speedup vs baseline: 1.5336x; 1.5336x over previous
//
#include <hip/hip_runtime.h>
#include <hip/hip_bf16.h>

#define HH 1024
#define NHEADS 8
#define HDIM 128
#define BB 4
#define TT 2048
#define MROWS (BB*TT)   // 8192

typedef __bf16 bf16;
typedef __bf16 bf16x4 __attribute__((ext_vector_type(4)));
typedef __bf16 bf16x8 __attribute__((ext_vector_type(8)));
typedef float floatx4 __attribute__((ext_vector_type(4)));

// async global->LDS DMA, 16B/lane; lds dest = wave-uniform base + lane*16
__device__ __forceinline__ void gl2lds16(const void* g, void* l) {
    __builtin_amdgcn_global_load_lds(
        (const __attribute__((address_space(1))) unsigned int*)g,
        (__attribute__((address_space(3))) unsigned int*)l, 16, 0, 0);
}

// ---------------- LayerNorm: one block per row, f32 in -> bf16 out ----------------
__global__ __launch_bounds__(256) void ln_k(const float* __restrict__ x,
                                            const float* __restrict__ g,
                                            const float* __restrict__ be,
                                            bf16* __restrict__ xn) {
    int row = blockIdx.x;
    int t = threadIdx.x;
    float4 v4 = ((const float4*)(x + (size_t)row * HH))[t];
    const float* v = (const float*)&v4;
    float s = v[0] + v[1] + v[2] + v[3];
    float s2 = v[0]*v[0] + v[1]*v[1] + v[2]*v[2] + v[3]*v[3];
#pragma unroll
    for (int off = 32; off > 0; off >>= 1) {
        s  += __shfl_down(s,  off);
        s2 += __shfl_down(s2, off);
    }
    __shared__ float red[8];
    if ((t & 63) == 0) { red[t >> 6] = s; red[(t >> 6) + 4] = s2; }
    __syncthreads();
    s  = red[0] + red[1] + red[2] + red[3];
    s2 = red[4] + red[5] + red[6] + red[7];
    float mu  = s * (1.f / HH);
    float var = s2 * (1.f / HH) - mu * mu;
    float rs  = rsqrtf(var + 1e-5f);
    float4 g4 = ((const float4*)g)[t];
    float4 b4 = ((const float4*)be)[t];
    const float* gv = (const float*)&g4;
    const float* bv = (const float*)&b4;
    bf16x4 o;
#pragma unroll
    for (int z = 0; z < 4; z++) o[z] = (bf16)((v[z] - mu) * rs * gv[z] + bv[z]);
    ((bf16x4*)(xn + (size_t)row * HH))[t] = o;
}

// ---------------- Weight convert f32 -> bf16 (1024x1024) ----------------
__global__ __launch_bounds__(256) void convw_k(const float* __restrict__ W,
                                               bf16* __restrict__ Wb) {
    int idx = blockIdx.x * 256 + threadIdx.x;
    float4 v4 = ((const float4*)W)[idx];
    const float* v = (const float*)&v4;
    bf16x4 o;
#pragma unroll
    for (int z = 0; z < 4; z++) o[z] = (bf16)v[z];
    ((bf16x4*)Wb)[idx] = o;
}

// ---- Fused QKV GEMM (M=8192, N=3072, K=1024), pure bf16, DMA staging ----
// Same inner loop as gemm_finbf_k. Column range selects output: Q / K / V^T.
__global__ __launch_bounds__(256) void gemm_qkvbf_k(const bf16* __restrict__ A,
                                                    const bf16* __restrict__ W,
                                                    bf16* __restrict__ Qb,
                                                    bf16* __restrict__ Kb,
                                                    bf16* __restrict__ Vb) {
    const int K = HH;
    __shared__ __align__(16) bf16 As[128 * 32];
    __shared__ __align__(16) bf16 Ws[128 * 32];
    int m0 = blockIdx.x * 128, n0 = blockIdx.y * 128;
    int t = threadIdx.x, lane = t & 63, w = t >> 6;
    int wm = w >> 1, wn = w & 1;
    int quad = lane >> 4, cl = lane & 15;
    int rA0 = w * 16 + (lane >> 2);
    int xa = (((lane & 3) ^ ((lane >> 3) & 3)) * 8);
    char* AsB = (char*)As + w * 1024;
    char* WsB = (char*)Ws + w * 1024;
    int pc = (quad ^ ((cl >> 1) & 3)) * 8;
    floatx4 acc[4][4] = {};
    for (int k0 = 0; k0 < K; k0 += 32) {
        __syncthreads();
#pragma unroll
        for (int i = 0; i < 2; i++) {
            gl2lds16(&A[(size_t)(m0 + rA0 + i * 64) * K + k0 + xa], AsB + i * 4096);
            gl2lds16(&W[(size_t)(n0 + rA0 + i * 64) * K + k0 + xa], WsB + i * 4096);
        }
        __syncthreads();
        bf16x8 af[4], bfr[4];
#pragma unroll
        for (int i = 0; i < 4; i++) af[i]  = *(const bf16x8*)&As[(wm * 64 + i * 16 + cl) * 32 + pc];
#pragma unroll
        for (int j = 0; j < 4; j++) bfr[j] = *(const bf16x8*)&Ws[(wn * 64 + j * 16 + cl) * 32 + pc];
#pragma unroll
        for (int i = 0; i < 4; i++)
#pragma unroll
            for (int j = 0; j < 4; j++)
                acc[i][j] = __builtin_amdgcn_mfma_f32_16x16x32_bf16(af[i], bfr[j], acc[i][j], 0, 0, 0);
    }
    // epilogue: n0 in [0,1024) -> Q, [1024,2048) -> K, [2048,3072) -> V^T
#pragma unroll
    for (int i = 0; i < 4; i++)
#pragma unroll
        for (int j = 0; j < 4; j++) {
            int gr = m0 + wm * 64 + i * 16 + quad * 4;
            int gn = n0 + wn * 64 + j * 16 + cl;
            if (n0 < 1024) {
#pragma unroll
                for (int rg = 0; rg < 4; rg++)
                    Qb[(size_t)(gr + rg) * HH + gn] = (bf16)acc[i][j][rg];
            } else if (n0 < 2048) {
#pragma unroll
                for (int rg = 0; rg < 4; rg++)
                    Kb[(size_t)(gr + rg) * HH + (gn - 1024)] = (bf16)acc[i][j][rg];
            } else {
                int gc = gn - 2048;
                int bb2 = gr >> 11, tt2 = gr & 2047;
                int hh2 = gc >> 7,  dd2 = gc & 127;
                bf16x4 o4;
#pragma unroll
                for (int rg = 0; rg < 4; rg++) o4[rg] = (bf16)acc[i][j][rg];
                *(bf16x4*)&Vb[((size_t)(bb2 * NHEADS + hh2) * HDIM + dd2) * TT + tt2] = o4;
            }
        }
}

// ------- 128x128 final GEMM (DMA staging): out_f32 = A_bf16 * Wb_bf16^T + R_f32 -------
__global__ __launch_bounds__(256) void gemm_finbf_k(const bf16* __restrict__ A,
                                                    const bf16* __restrict__ W,
                                                    const float* __restrict__ R,
                                                    float* __restrict__ C) {
    const int K = HH, N = HH;
    __shared__ __align__(16) bf16 As[128 * 32];
    __shared__ __align__(16) bf16 Ws[128 * 32];
    int m0 = blockIdx.x * 128, n0 = blockIdx.y * 128;
    int t = threadIdx.x, lane = t & 63, w = t >> 6;
    int wm = w >> 1, wn = w & 1;
    int quad = lane >> 4, cl = lane & 15;
    int rA0 = w * 16 + (lane >> 2);
    int xa = (((lane & 3) ^ ((lane >> 3) & 3)) * 8);
    char* AsB = (char*)As + w * 1024;
    char* WsB = (char*)Ws + w * 1024;
    int pc = (quad ^ ((cl >> 1) & 3)) * 8;
    floatx4 acc[4][4] = {};
    for (int k0 = 0; k0 < K; k0 += 32) {
        __syncthreads();
#pragma unroll
        for (int i = 0; i < 2; i++) {
            gl2lds16(&A[(size_t)(m0 + rA0 + i * 64) * K + k0 + xa], AsB + i * 4096);
            gl2lds16(&W[(size_t)(n0 + rA0 + i * 64) * K + k0 + xa], WsB + i * 4096);
        }
        __syncthreads();
        bf16x8 af[4], bfr[4];
#pragma unroll
        for (int i = 0; i < 4; i++) af[i]  = *(const bf16x8*)&As[(wm * 64 + i * 16 + cl) * 32 + pc];
#pragma unroll
        for (int j = 0; j < 4; j++) bfr[j] = *(const bf16x8*)&Ws[(wn * 64 + j * 16 + cl) * 32 + pc];
#pragma unroll
        for (int i = 0; i < 4; i++)
#pragma unroll
            for (int j = 0; j < 4; j++)
                acc[i][j] = __builtin_amdgcn_mfma_f32_16x16x32_bf16(af[i], bfr[j], acc[i][j], 0, 0, 0);
    }
#pragma unroll
    for (int i = 0; i < 4; i++)
#pragma unroll
        for (int j = 0; j < 4; j++)
#pragma unroll
            for (int rg = 0; rg < 4; rg++) {
                int gr = m0 + wm * 64 + i * 16 + quad * 4 + rg;
                int gc = n0 + wn * 64 + j * 16 + cl;
                C[(size_t)gr * N + gc] = acc[i][j][rg] + R[(size_t)gr * N + gc];
            }
}

// ---- Flash attention (causal): 128-row Q tile, Q frags from global, ----
// ---- single-buffered padded K/V with VGPR prefetch. NO occupancy cap ----
// ---- (round-9's __launch_bounds__(256,3) caused 84-VGPR spills, 273MB scratch) ----
__global__ __launch_bounds__(256) void attn_k(const bf16* __restrict__ Q,
                                              const bf16* __restrict__ Kg,
                                              const bf16* __restrict__ Vt,
                                              bf16* __restrict__ O) {
    __shared__ __align__(16) bf16 Ks[64 * 136];   // 17408 B
    __shared__ __align__(16) bf16 Vs[128 * 72];   // 18432 B -> 35840 B total

    int qt = gridDim.x - 1 - blockIdx.x;  // longest blocks first
    int h = blockIdx.y, b = blockIdx.z;
    int t = threadIdx.x, lane = t & 63, w = t >> 6;
    int quad = lane >> 4, cl = lane & 15;
    size_t rowbase = (size_t)b * TT;
    int q0 = qt * 128;
    size_t hcol = (size_t)h * HDIM;
    size_t vtbase = (size_t)(b * NHEADS + h) * HDIM * TT;

    // Q fragments straight from global (one-time; L2-warm)
    bf16x8 qf[4][2];
#pragma unroll
    for (int kk = 0; kk < 4; kk++)
#pragma unroll
        for (int g = 0; g < 2; g++)
            qf[kk][g] = *(const bf16x8*)&Q[(rowbase + q0 + w * 32 + g * 16 + cl) * HH + hcol + kk * 32 + quad * 8];

    float m_i[2] = {-1e30f, -1e30f}, l_i[2] = {0.f, 0.f};
    floatx4 acc[8][2] = {};
    const float scale = 0.08838834764831845f;  // 1/sqrt(128)

    bf16x8 kr[4], vr[4];
    auto fetch = [&](int ktf) {
#pragma unroll
        for (int i = 0; i < 4; i++) {
            int e = t + i * 256;
            kr[i] = *(const bf16x8*)&Kg[(rowbase + (size_t)ktf * 64 + (e >> 4)) * HH + hcol + (e & 15) * 8];
            vr[i] = *(const bf16x8*)&Vt[vtbase + (size_t)(e >> 3) * TT + ktf * 64 + (e & 7) * 8];
        }
    };
    fetch(0);
    int ktmax = 2 * qt + 1;

    for (int kt = 0; kt <= ktmax; kt++) {
        __syncthreads();  // prev iter's frag reads complete
#pragma unroll
        for (int i = 0; i < 4; i++) {
            int e = t + i * 256;
            *(bf16x8*)&Ks[(e >> 4) * 136 + (e & 15) * 8] = kr[i];
            *(bf16x8*)&Vs[(e >> 3) * 72 + (e & 7) * 8]   = vr[i];
        }
        if (kt < ktmax) fetch(kt + 1);  // in flight across whole body
        __syncthreads();

        // S^T: A = K-frag (shared by both q-groups), B = Q-frag
        floatx4 sacc[2][4] = {};
#pragma unroll
        for (int kk = 0; kk < 4; kk++)
#pragma unroll
            for (int jj = 0; jj < 4; jj++) {
                bf16x8 ak = *(const bf16x8*)&Ks[(jj * 16 + cl) * 136 + kk * 32 + quad * 8];
                sacc[0][jj] = __builtin_amdgcn_mfma_f32_16x16x32_bf16(ak, qf[kk][0], sacc[0][jj], 0, 0, 0);
                sacc[1][jj] = __builtin_amdgcn_mfma_f32_16x16x32_bf16(ak, qf[kk][1], sacc[1][jj], 0, 0, 0);
            }

        float pp[2][4][4], alpha[2];
        bool diag = (kt >= 2 * qt);
#pragma unroll
        for (int g = 0; g < 2; g++) {
            int qglob = q0 + w * 32 + g * 16 + cl;
            float mx = -1e30f;
#pragma unroll
            for (int jj = 0; jj < 4; jj++)
#pragma unroll
                for (int rg = 0; rg < 4; rg++) {
                    float sv = sacc[g][jj][rg] * scale;
                    if (diag && (kt * 64 + jj * 16 + quad * 4 + rg) > qglob) sv = -1e30f;
                    pp[g][jj][rg] = sv;
                    mx = fmaxf(mx, sv);
                }
            mx = fmaxf(mx, __shfl_xor(mx, 16));
            mx = fmaxf(mx, __shfl_xor(mx, 32));
            float mn = fmaxf(m_i[g], mx);
            alpha[g] = __expf(m_i[g] - mn);
            m_i[g] = mn;
            float sum = 0.f;
#pragma unroll
            for (int jj = 0; jj < 4; jj++)
#pragma unroll
                for (int rg = 0; rg < 4; rg++) {
                    float pe = __expf(pp[g][jj][rg] - mn);
                    pp[g][jj][rg] = pe;
                    sum += pe;
                }
            sum += __shfl_xor(sum, 16);
            sum += __shfl_xor(sum, 32);
            l_i[g] = l_i[g] * alpha[g] + sum;
        }

        int pk[2][4][2];
#pragma unroll
        for (int g = 0; g < 2; g++)
#pragma unroll
            for (int jj = 0; jj < 4; jj++) {
                union { bf16x4 v; int i2[2]; } u;
#pragma unroll
                for (int rg = 0; rg < 4; rg++) u.v[rg] = (bf16)pp[g][jj][rg];
                pk[g][jj][0] = u.i2[0];
                pk[g][jj][1] = u.i2[1];
            }
#pragma unroll
        for (int nt = 0; nt < 8; nt++) {
            acc[nt][0] *= alpha[0];
            acc[nt][1] *= alpha[1];
        }

        int La = ((2 * quad) & 3) * 16 + cl;
        int Lb = ((2 * quad + 1) & 3) * 16 + cl;
        bool hi = (quad >> 1) & 1;
#pragma unroll
        for (int kti = 0; kti < 2; kti++) {
            int j0 = kti * 2, j1 = kti * 2 + 1;
            union { bf16x8 v; int i4[4]; } pu[2];
#pragma unroll
            for (int g = 0; g < 2; g++) {
                int a0x = __shfl(pk[g][j0][0], La), a0y = __shfl(pk[g][j0][1], La);
                int a1x = __shfl(pk[g][j1][0], La), a1y = __shfl(pk[g][j1][1], La);
                int b0x = __shfl(pk[g][j0][0], Lb), b0y = __shfl(pk[g][j0][1], Lb);
                int b1x = __shfl(pk[g][j1][0], Lb), b1y = __shfl(pk[g][j1][1], Lb);
                pu[g].i4[0] = hi ? a1x : a0x;
                pu[g].i4[1] = hi ? a1y : a0y;
                pu[g].i4[2] = hi ? b1x : b0x;
                pu[g].i4[3] = hi ? b1y : b0y;
            }
#pragma unroll
            for (int nt = 0; nt < 8; nt++) {
                bf16x8 av = *(const bf16x8*)&Vs[(nt * 16 + cl) * 72 + kti * 32 + quad * 8];
                acc[nt][0] = __builtin_amdgcn_mfma_f32_16x16x32_bf16(av, pu[0].v, acc[nt][0], 0, 0, 0);
                acc[nt][1] = __builtin_amdgcn_mfma_f32_16x16x32_bf16(av, pu[1].v, acc[nt][1], 0, 0, 0);
            }
        }
    }

    float linv[2] = {1.f / l_i[0], 1.f / l_i[1]};
#pragma unroll
    for (int g = 0; g < 2; g++)
#pragma unroll
        for (int nt = 0; nt < 8; nt++) {
            bf16x4 o4;
#pragma unroll
            for (int rg = 0; rg < 4; rg++) o4[rg] = (bf16)(acc[nt][g][rg] * linv[g]);
            *(bf16x4*)&O[(rowbase + q0 + w * 32 + g * 16 + cl) * HH + hcol + nt * 16 + quad * 4] = o4;
        }
}

extern "C" void kernel_launch(void* const* d_in, const int* in_sizes, int n_in,
                              void* d_out, int out_size, void* d_ws, size_t ws_size,
                              hipStream_t stream) {
    const float* x     = (const float*)d_in[0];
    const float* gamma = (const float*)d_in[1];
    const float* beta  = (const float*)d_in[2];
    const float* Wq    = (const float*)d_in[3];
    const float* Wk    = (const float*)d_in[4];
    const float* Wv    = (const float*)d_in[5];
    const float* Wo    = (const float*)d_in[6];
    float* out = (float*)d_out;

    const size_t NELEM = (size_t)MROWS * HH;  // 8.39M
    const size_t NW    = (size_t)HH * HH;     // 1.05M
    // ws (39.9 MB): Qb bf16 + Vb bf16 + Wqkv bf16 (6.3 MB).
    // d_out (33.5 MB f32): Kb bf16 [0,16.8M) + xnb bf16 [16.8M,33.5M) —
    // both dead before the final GEMM writes d_out. Attn output aliases Qb;
    // Wo-bf16 parked in Vb after attn (Vb dead then).
    bf16* Qb   = (bf16*)d_ws;
    bf16* Vb   = Qb + NELEM;           // V^T layout [b][h][d][T]
    bf16* Wqkv = Vb + NELEM;           // 3072x1024 bf16
    bf16* Kb   = (bf16*)d_out;
    bf16* xnb  = (bf16*)d_out + NELEM;

    ln_k<<<MROWS, 256, 0, stream>>>(x, gamma, beta, xnb);
    convw_k<<<NW / 1024, 256, 0, stream>>>(Wq, Wqkv);
    convw_k<<<NW / 1024, 256, 0, stream>>>(Wk, Wqkv + NW);
    convw_k<<<NW / 1024, 256, 0, stream>>>(Wv, Wqkv + 2 * NW);
    gemm_qkvbf_k<<<dim3(MROWS / 128, 24), 256, 0, stream>>>(xnb, Wqkv, Qb, Kb, Vb);
    attn_k<<<dim3(TT / 128, NHEADS, BB), 256, 0, stream>>>(Qb, Kb, Vb, Qb);
    convw_k<<<NW / 1024, 256, 0, stream>>>(Wo, Vb);
    gemm_finbf_k<<<dim3(MROWS / 128, HH / 128), 256, 0, stream>>>(Qb, Vb, x, out);
}